// Round 1
// baseline (573.416 us; speedup 1.0000x reference)
//
#include <hip/hip_runtime.h>

typedef __attribute__((ext_vector_type(8))) short short8;
typedef __attribute__((ext_vector_type(4))) float float4v;

#define V_ 20000

__device__ __forceinline__ unsigned short f2bf(float f) {
    union { float f; unsigned int u; } v; v.f = f;
    unsigned int u = v.u;
    u += 0x7fffu + ((u >> 16) & 1u);
    return (unsigned short)(u >> 16);
}

__device__ __forceinline__ float fast_tanh(float x) {
    float xc = fminf(15.f, fmaxf(-15.f, x));
    float e = __expf(2.f * xc);
    return (e - 1.f) / (e + 1.f);   // tanh(0) == 0 exactly (mask depends on it)
}

__device__ __forceinline__ float sigmoidf_(float x) {
    float xc = fminf(30.f, fmaxf(-30.f, x));
    return 1.f / (1.f + __expf(-xc));
}

#define GLL16(gp, lp) __builtin_amdgcn_global_load_lds( \
    (const __attribute__((address_space(1))) void*)(gp), \
    (__attribute__((address_space(3))) void*)(lp), 16, 0, 0)

// ---------------------------------------------------------------- cvt emb -> bf16 transposed [128n][20000k]
// Also zeroes the split-K accumulator xeacc (must run before big_gemm; re-done each launch/replay).
__global__ __launch_bounds__(256) void cvt_embT(const float* __restrict__ emb,
                                                unsigned short* __restrict__ embT,
                                                float* __restrict__ xeacc) {
    int tid = threadIdx.x;
    int gid = blockIdx.x * 256 + tid;
    for (int i = gid; i < 3328 * 128; i += 313 * 256) xeacc[i] = 0.f;

    __shared__ unsigned short tile[128 * 65];
    int k0 = blockIdx.x * 64;
    const float4v* e4 = (const float4v*)emb;
    #pragma unroll
    for (int c = 0; c < 8; ++c) {
        int l4 = c * 256 + tid;      // float4 index in 64k x 128n tile
        int k = l4 >> 5;             // 32 float4 per k-row
        int n4 = l4 & 31;
        float4v f = {0.f, 0.f, 0.f, 0.f};
        if (k0 + k < V_) f = e4[(size_t)(k0 + k) * 32 + n4];
        tile[(n4 * 4 + 0) * 65 + k] = f2bf(f.x);
        tile[(n4 * 4 + 1) * 65 + k] = f2bf(f.y);
        tile[(n4 * 4 + 2) * 65 + k] = f2bf(f.z);
        tile[(n4 * 4 + 3) * 65 + k] = f2bf(f.w);
    }
    __syncthreads();
    #pragma unroll
    for (int c = 0; c < 4; ++c) {
        int l8 = c * 256 + tid;      // n*8 + seg
        int n = l8 >> 3, seg = l8 & 7;
        int kk = k0 + seg * 8;
        if (kk < V_) {
            short8 v;
            #pragma unroll
            for (int i = 0; i < 8; ++i) v[i] = (short)tile[n * 65 + seg * 8 + i];
            *(short8*)(embT + (size_t)n * V_ + kk) = v;
        }
    }
}

// ---------------------------------------------------------------- big GEMM: xeacc[3328][128] += rows @ emb
// rows 0..3199 = x, 3200..3231 = a, rest padding. Double-buffered LDS,
// B staged via global_load_lds DMA (unpadded layout), A prefetched in regs.
// Split-K epilogue: HW f32 atomics into xeacc (no partial buffer round-trip).
__global__ __launch_bounds__(256, 4) void big_gemm(const float* __restrict__ x,
                                                   const float* __restrict__ a,
                                                   const unsigned short* __restrict__ embT,
                                                   float* __restrict__ xeacc,
                                                   int ks) {
    __shared__ unsigned short Alds[2][128 * 40];   // bf16, padded stride 40
    __shared__ unsigned short Blds[2][128 * 32];   // bf16, unpadded (DMA target)
    int tid = threadIdx.x;
    int bx = blockIdx.x, by = blockIdx.y;
    int m0 = bx * 128;
    int per = 625 / ks, extra = 625 % ks;
    int kb0 = by * per + (by < extra ? by : extra);
    int nkb = per + (by < extra ? 1 : 0);

    int lane = tid & 63, wave = tid >> 6;
    int wr = wave >> 1, wc = wave & 1;
    int ln = lane & 15, quad = lane >> 4;

    float4v acc[4][4];
    #pragma unroll
    for (int i = 0; i < 4; ++i)
        #pragma unroll
        for (int j = 0; j < 4; ++j) acc[i][j] = (float4v){0.f, 0.f, 0.f, 0.f};

    int row = tid >> 1, seg = tid & 1;
    int rg = m0 + row;
    int aidx = rg - 3200; aidx = aidx < 0 ? 0 : (aidx > 31 ? 31 : aidx);
    const float* __restrict__ srcA = (rg < 3200) ? (x + (size_t)rg * V_)
                                                 : (a + (size_t)aidx * V_);
    // B DMA mapping: call q in {0,1}: chunk c = q*256 + tid; brow=c>>2, bkq=c&3
    int brow0 = tid >> 2, bkq = tid & 3;
    int wbase = tid & ~63;                     // wave-uniform chunk base (q=0)
    const unsigned short* gB0 = embT + (size_t)brow0 * V_ + bkq * 8;
    const unsigned short* gB1 = embT + (size_t)(64 + brow0) * V_ + bkq * 8;

    float4v fa0, fa1, fa2, fa3;

    // ---- prologue: stage tile 0 into buf 0
    {
        int k0 = kb0 * 32;
        const float4v* ap = (const float4v*)(srcA + k0 + seg * 16);
        fa0 = ap[0]; fa1 = ap[1]; fa2 = ap[2]; fa3 = ap[3];
        GLL16(gB0 + k0, &Blds[0][(size_t)wbase * 8]);
        GLL16(gB1 + k0, &Blds[0][(size_t)(256 + wbase) * 8]);
        short8 w0, w1;
        w0[0]=(short)f2bf(fa0.x); w0[1]=(short)f2bf(fa0.y); w0[2]=(short)f2bf(fa0.z); w0[3]=(short)f2bf(fa0.w);
        w0[4]=(short)f2bf(fa1.x); w0[5]=(short)f2bf(fa1.y); w0[6]=(short)f2bf(fa1.z); w0[7]=(short)f2bf(fa1.w);
        w1[0]=(short)f2bf(fa2.x); w1[1]=(short)f2bf(fa2.y); w1[2]=(short)f2bf(fa2.z); w1[3]=(short)f2bf(fa2.w);
        w1[4]=(short)f2bf(fa3.x); w1[5]=(short)f2bf(fa3.y); w1[6]=(short)f2bf(fa3.z); w1[7]=(short)f2bf(fa3.w);
        *(short8*)&Alds[0][row * 40 + seg * 16]     = w0;
        *(short8*)&Alds[0][row * 40 + seg * 16 + 8] = w1;
    }
    __syncthreads();

    for (int it = 0; it < nkb; ++it) {
        int buf = it & 1, nxt = buf ^ 1;
        bool more = (it + 1 < nkb);
        if (more) {
            int k0 = (kb0 + it + 1) * 32;
            const float4v* ap = (const float4v*)(srcA + k0 + seg * 16);
            fa0 = ap[0]; fa1 = ap[1]; fa2 = ap[2]; fa3 = ap[3];
            GLL16(gB0 + k0, &Blds[nxt][(size_t)wbase * 8]);
            GLL16(gB1 + k0, &Blds[nxt][(size_t)(256 + wbase) * 8]);
        }
        short8 af[4];
        #pragma unroll
        for (int i = 0; i < 4; ++i)
            af[i] = *(const short8*)&Alds[buf][(wr * 64 + i * 16 + ln) * 40 + quad * 8];
        #pragma unroll
        for (int j = 0; j < 4; ++j) {
            short8 bf = *(const short8*)&Blds[buf][(wc * 64 + j * 16 + ln) * 32 + quad * 8];
            #pragma unroll
            for (int i = 0; i < 4; ++i)
                acc[i][j] = __builtin_amdgcn_mfma_f32_16x16x32_bf16(af[i], bf, acc[i][j], 0, 0, 0);
        }
        if (more) {
            short8 w0, w1;
            w0[0]=(short)f2bf(fa0.x); w0[1]=(short)f2bf(fa0.y); w0[2]=(short)f2bf(fa0.z); w0[3]=(short)f2bf(fa0.w);
            w0[4]=(short)f2bf(fa1.x); w0[5]=(short)f2bf(fa1.y); w0[6]=(short)f2bf(fa1.z); w0[7]=(short)f2bf(fa1.w);
            w1[0]=(short)f2bf(fa2.x); w1[1]=(short)f2bf(fa2.y); w1[2]=(short)f2bf(fa2.z); w1[3]=(short)f2bf(fa2.w);
            w1[4]=(short)f2bf(fa3.x); w1[5]=(short)f2bf(fa3.y); w1[6]=(short)f2bf(fa3.z); w1[7]=(short)f2bf(fa3.w);
            *(short8*)&Alds[nxt][row * 40 + seg * 16]     = w0;
            *(short8*)&Alds[nxt][row * 40 + seg * 16 + 8] = w1;
        }
        __syncthreads();
    }

    // atomic split-K epilogue (global_atomic_add_f32; 64B-coalesced per quarter-wave)
    #pragma unroll
    for (int i = 0; i < 4; ++i) {
        #pragma unroll
        for (int j = 0; j < 4; ++j) {
            int rowb = m0 + wr * 64 + i * 16 + quad * 4;
            int col = wc * 64 + j * 16 + ln;
            #pragma unroll
            for (int r = 0; r < 4; ++r)
                unsafeAtomicAdd(&xeacc[(size_t)(rowb + r) * 128 + col], acc[i][j][r]);
        }
    }
}

// ---------------------------------------------------------------- fused: tanh+mask of xeacc -> xproj = xe @ gru_k + b_i
// blocks 0..199: 16 x-rows each (xe never hits global memory). block 200: ae rows.
__global__ __launch_bounds__(384) void xproj_fused(const float* __restrict__ xeacc,
                                                   const float* __restrict__ gru_k,
                                                   const float* __restrict__ b_i,
                                                   float* __restrict__ xproj,
                                                   float* __restrict__ maskg,
                                                   float* __restrict__ ae) {
    int tid = threadIdx.x;
    if (blockIdx.x == 200) {                       // a-embedding rows 3200..3231
        for (int i = tid; i < 32 * 128; i += 384)
            ae[i] = fast_tanh(xeacc[3200 * 128 + i]);
        return;
    }
    __shared__ float xs[16 * 128];
    __shared__ int anyr[16];
    int row0 = blockIdx.x * 16;
    if (tid < 16) anyr[tid] = 0;
    __syncthreads();
    for (int i = tid; i < 2048; i += 384) {
        float v = fast_tanh(xeacc[(size_t)row0 * 128 + i]);
        xs[i] = v;
        if (v != 0.f) anyr[i >> 7] = 1;            // benign race: all writers store 1
    }
    __syncthreads();
    if (tid < 16) maskg[row0 + tid] = anyr[tid] ? 1.f : 0.f;

    int j = tid;  // 0..383
    float acc[16];
    #pragma unroll
    for (int r = 0; r < 16; ++r) acc[r] = 0.f;
    float bi = b_i[j];
    for (int k4 = 0; k4 < 32; ++k4) {
        float g0 = gru_k[(k4 * 4 + 0) * 384 + j];
        float g1 = gru_k[(k4 * 4 + 1) * 384 + j];
        float g2 = gru_k[(k4 * 4 + 2) * 384 + j];
        float g3 = gru_k[(k4 * 4 + 3) * 384 + j];
        #pragma unroll
        for (int r = 0; r < 16; ++r) {
            float4v xv = *(const float4v*)&xs[r * 128 + k4 * 4];
            acc[r] = fmaf(xv.x, g0, acc[r]);
            acc[r] = fmaf(xv.y, g1, acc[r]);
            acc[r] = fmaf(xv.z, g2, acc[r]);
            acc[r] = fmaf(xv.w, g3, acc[r]);
        }
    }
    #pragma unroll
    for (int r = 0; r < 16; ++r)
        xproj[(size_t)(row0 + r) * 384 + j] = acc[r] + bi;
}

// ---------------------------------------------------------------- GRU scan + fused head: 1 block / batch
__global__ __launch_bounds__(384) void gru_fused(const float* __restrict__ xproj,
                                                 const float* __restrict__ maskg,
                                                 const float* __restrict__ gru_rk,
                                                 const float* __restrict__ b_r,
                                                 const float* __restrict__ ae,
                                                 const float* __restrict__ d,
                                                 const float* __restrict__ W1,
                                                 const float* __restrict__ b1,
                                                 const float* __restrict__ W2,
                                                 const float* __restrict__ b2,
                                                 float* __restrict__ out) {
    int b = blockIdx.x;
    int j = threadIdx.x;  // 0..383
    float w[128];
    #pragma unroll
    for (int k = 0; k < 128; ++k) w[k] = gru_rk[k * 384 + j];
    float br = b_r[j];
    __shared__ float4v hs4[32];
    __shared__ float recs[384];
    float* hs = (float*)hs4;
    float hreg = 0.f;
    if (j < 128) hs[j] = 0.f;
    const float* xp_base = xproj + (size_t)b * 100 * 384;
    const float* mk = maskg + b * 100;
    // prefetched gate inputs for j<128 threads
    float xz = 0.f, xr = 0.f, xh = 0.f;
    if (j < 128) { xz = xp_base[j]; xr = xp_base[128 + j]; xh = xp_base[256 + j]; }
    __syncthreads();
    for (int t = 0; t < 100; ++t) {
        // prefetch next step's gate inputs (latency hidden behind matvec + gates)
        float nxz = 0.f, nxr = 0.f, nxh = 0.f;
        if (t < 99 && j < 128) {
            const float* nb = xp_base + (t + 1) * 384;
            nxz = nb[j]; nxr = nb[128 + j]; nxh = nb[256 + j];
        }
        float s0 = 0.f, s1 = 0.f, s2 = 0.f, s3 = 0.f;
        #pragma unroll
        for (int k4 = 0; k4 < 32; ++k4) {
            float4v hv = hs4[k4];
            s0 = fmaf(hv.x, w[k4 * 4 + 0], s0);
            s1 = fmaf(hv.y, w[k4 * 4 + 1], s1);
            s2 = fmaf(hv.z, w[k4 * 4 + 2], s2);
            s3 = fmaf(hv.w, w[k4 * 4 + 3], s3);
        }
        recs[j] = br + ((s0 + s1) + (s2 + s3));
        __syncthreads();
        if (j < 128) {
            float z = sigmoidf_(xz + recs[j]);
            float r = sigmoidf_(xr + recs[128 + j]);
            float hh = fast_tanh(xh + r * recs[256 + j]);
            float hn = z * hreg + (1.f - z) * hh;
            hreg = (mk[t] != 0.f) ? hn : hreg;
            hs[j] = hreg;
        }
        __syncthreads();
        xz = nxz; xr = nxr; xh = nxh;
    }
    // ---- fused head: h is complete in hs[] after the final barrier
    if (j < 64) {
        int m = j;
        float s = b1[m];
        const float* ab = ae + b * 128;
        #pragma unroll 4
        for (int k = 0; k < 128; ++k) s = fmaf(hs[k], W1[k * 64 + m], s);
        #pragma unroll 4
        for (int k = 0; k < 128; ++k) s = fmaf(ab[k], W1[(128 + k) * 64 + m], s);
        float c = fast_tanh(s);
        float p = c * W2[m];
        #pragma unroll
        for (int off = 32; off > 0; off >>= 1) p += __shfl_down(p, off);
        if (m == 0) {
            p += d[b * 2 + 0] * W2[64] + d[b * 2 + 1] * W2[65] + b2[0];
            out[b] = sigmoidf_(p);
        }
    }
}

extern "C" void kernel_launch(void* const* d_in, const int* in_sizes, int n_in,
                              void* d_out, int out_size, void* d_ws, size_t ws_size,
                              hipStream_t stream) {
    (void)in_sizes; (void)n_in; (void)out_size; (void)ws_size;
    const float* x      = (const float*)d_in[0];
    const float* a      = (const float*)d_in[1];
    const float* d      = (const float*)d_in[2];
    const float* emb    = (const float*)d_in[3];
    const float* gru_k  = (const float*)d_in[4];
    const float* gru_rk = (const float*)d_in[5];
    const float* gbi    = (const float*)d_in[6];
    const float* gbr    = (const float*)d_in[7];
    const float* W1     = (const float*)d_in[8];
    const float* b1     = (const float*)d_in[9];
    const float* W2     = (const float*)d_in[10];
    const float* b2     = (const float*)d_in[11];
    float* out = (float*)d_out;

    char* ws = (char*)d_ws;
    unsigned short* embT = (unsigned short*)(ws);              //  5,120,000 B
    float* xeacc   = (float*)(ws + 5120000);                   //  1,703,936 B (3328*128 f32)
    float* ae      = (float*)(ws + 6823936);                   //     16,384 B
    float* maskg   = (float*)(ws + 6840320);                   //     12,800 B
    float* xproj   = (float*)(ws + 6853120);                   //  4,915,200 B -> 11,768,320 total

    const int ks = 32;   // split-K slices (atomic accumulation: no partial buffer)

    hipLaunchKernelGGL(cvt_embT,    dim3(313),    dim3(256), 0, stream, emb, embT, xeacc);
    hipLaunchKernelGGL(big_gemm,    dim3(26, ks), dim3(256), 0, stream, x, a, embT, xeacc, ks);
    hipLaunchKernelGGL(xproj_fused, dim3(201),    dim3(384), 0, stream, xeacc, gru_k, gbi, xproj, maskg, ae);
    hipLaunchKernelGGL(gru_fused,   dim3(32),     dim3(384), 0, stream, xproj, maskg, gru_rk, gbr,
                       ae, d, W1, b1, W2, b2, out);
}

// Round 3
// 564.855 us; speedup vs baseline: 1.0152x; 1.0152x over previous
//
#include <hip/hip_runtime.h>

typedef __attribute__((ext_vector_type(8))) short short8;
typedef __attribute__((ext_vector_type(4))) float float4v;

#define V_ 20000

__device__ __forceinline__ unsigned short f2bf(float f) {
    union { float f; unsigned int u; } v; v.f = f;
    unsigned int u = v.u;
    u += 0x7fffu + ((u >> 16) & 1u);
    return (unsigned short)(u >> 16);
}

__device__ __forceinline__ float fast_tanh(float x) {
    float xc = fminf(15.f, fmaxf(-15.f, x));
    float e = __expf(2.f * xc);
    return (e - 1.f) / (e + 1.f);   // tanh(0) == 0 exactly (mask depends on it)
}

__device__ __forceinline__ float sigmoidf_(float x) {
    float xc = fminf(30.f, fmaxf(-30.f, x));
    return 1.f / (1.f + __expf(-xc));
}

#define GLL16(gp, lp) __builtin_amdgcn_global_load_lds( \
    (const __attribute__((address_space(1))) void*)(gp), \
    (__attribute__((address_space(3))) void*)(lp), 16, 0, 0)

// ---------------------------------------------------------------- cvt emb -> bf16 transposed [128n][20000k]
__global__ __launch_bounds__(256) void cvt_embT(const float* __restrict__ emb,
                                                unsigned short* __restrict__ embT) {
    __shared__ unsigned short tile[128 * 65];
    int tid = threadIdx.x;
    int k0 = blockIdx.x * 64;
    const float4v* e4 = (const float4v*)emb;
    #pragma unroll
    for (int c = 0; c < 8; ++c) {
        int l4 = c * 256 + tid;      // float4 index in 64k x 128n tile
        int k = l4 >> 5;             // 32 float4 per k-row
        int n4 = l4 & 31;
        float4v f = {0.f, 0.f, 0.f, 0.f};
        if (k0 + k < V_) f = e4[(size_t)(k0 + k) * 32 + n4];
        tile[(n4 * 4 + 0) * 65 + k] = f2bf(f.x);
        tile[(n4 * 4 + 1) * 65 + k] = f2bf(f.y);
        tile[(n4 * 4 + 2) * 65 + k] = f2bf(f.z);
        tile[(n4 * 4 + 3) * 65 + k] = f2bf(f.w);
    }
    __syncthreads();
    #pragma unroll
    for (int c = 0; c < 4; ++c) {
        int l8 = c * 256 + tid;      // n*8 + seg
        int n = l8 >> 3, seg = l8 & 7;
        int kk = k0 + seg * 8;
        if (kk < V_) {
            short8 v;
            #pragma unroll
            for (int i = 0; i < 8; ++i) v[i] = (short)tile[n * 65 + seg * 8 + i];
            *(short8*)(embT + (size_t)n * V_ + kk) = v;
        }
    }
}

// ---------------------------------------------------------------- big GEMM: partial[ks][3328][128] = rows @ emb
// rows 0..3199 = x, 3200..3231 = a, rest padding. Double-buffered LDS,
// B staged via global_load_lds DMA (unpadded layout), A prefetched in regs.
// Plain coalesced stores per K-slice (NO atomics: ks=32 atomics cost ~35-40 us
// in round 1 — 13.6M L2 atomic ops; compact partial round-trip is LLC-resident).
__global__ __launch_bounds__(256, 4) void big_gemm(const float* __restrict__ x,
                                                   const float* __restrict__ a,
                                                   const unsigned short* __restrict__ embT,
                                                   float* __restrict__ partial,
                                                   int ks) {
    __shared__ unsigned short Alds[2][128 * 40];   // bf16, padded stride 40
    __shared__ unsigned short Blds[2][128 * 32];   // bf16, unpadded (DMA target)
    int tid = threadIdx.x;
    int bx = blockIdx.x, by = blockIdx.y;
    int m0 = bx * 128;
    int per = 625 / ks, extra = 625 % ks;
    int kb0 = by * per + (by < extra ? by : extra);
    int nkb = per + (by < extra ? 1 : 0);

    int lane = tid & 63, wave = tid >> 6;
    int wr = wave >> 1, wc = wave & 1;
    int ln = lane & 15, quad = lane >> 4;

    float4v acc[4][4];
    #pragma unroll
    for (int i = 0; i < 4; ++i)
        #pragma unroll
        for (int j = 0; j < 4; ++j) acc[i][j] = (float4v){0.f, 0.f, 0.f, 0.f};

    int row = tid >> 1, seg = tid & 1;
    int rg = m0 + row;
    int aidx = rg - 3200; aidx = aidx < 0 ? 0 : (aidx > 31 ? 31 : aidx);
    const float* __restrict__ srcA = (rg < 3200) ? (x + (size_t)rg * V_)
                                                 : (a + (size_t)aidx * V_);
    // B DMA mapping: call q in {0,1}: chunk c = q*256 + tid; brow=c>>2, bkq=c&3
    int brow0 = tid >> 2, bkq = tid & 3;
    int wbase = tid & ~63;                     // wave-uniform chunk base (q=0)
    const unsigned short* gB0 = embT + (size_t)brow0 * V_ + bkq * 8;
    const unsigned short* gB1 = embT + (size_t)(64 + brow0) * V_ + bkq * 8;

    float4v fa0, fa1, fa2, fa3;

    // ---- prologue: stage tile 0 into buf 0
    {
        int k0 = kb0 * 32;
        const float4v* ap = (const float4v*)(srcA + k0 + seg * 16);
        fa0 = ap[0]; fa1 = ap[1]; fa2 = ap[2]; fa3 = ap[3];
        GLL16(gB0 + k0, &Blds[0][(size_t)wbase * 8]);
        GLL16(gB1 + k0, &Blds[0][(size_t)(256 + wbase) * 8]);
        short8 w0, w1;
        w0[0]=(short)f2bf(fa0.x); w0[1]=(short)f2bf(fa0.y); w0[2]=(short)f2bf(fa0.z); w0[3]=(short)f2bf(fa0.w);
        w0[4]=(short)f2bf(fa1.x); w0[5]=(short)f2bf(fa1.y); w0[6]=(short)f2bf(fa1.z); w0[7]=(short)f2bf(fa1.w);
        w1[0]=(short)f2bf(fa2.x); w1[1]=(short)f2bf(fa2.y); w1[2]=(short)f2bf(fa2.z); w1[3]=(short)f2bf(fa2.w);
        w1[4]=(short)f2bf(fa3.x); w1[5]=(short)f2bf(fa3.y); w1[6]=(short)f2bf(fa3.z); w1[7]=(short)f2bf(fa3.w);
        *(short8*)&Alds[0][row * 40 + seg * 16]     = w0;
        *(short8*)&Alds[0][row * 40 + seg * 16 + 8] = w1;
    }
    __syncthreads();

    for (int it = 0; it < nkb; ++it) {
        int buf = it & 1, nxt = buf ^ 1;
        bool more = (it + 1 < nkb);
        if (more) {
            int k0 = (kb0 + it + 1) * 32;
            const float4v* ap = (const float4v*)(srcA + k0 + seg * 16);
            fa0 = ap[0]; fa1 = ap[1]; fa2 = ap[2]; fa3 = ap[3];
            GLL16(gB0 + k0, &Blds[nxt][(size_t)wbase * 8]);
            GLL16(gB1 + k0, &Blds[nxt][(size_t)(256 + wbase) * 8]);
        }
        short8 af[4];
        #pragma unroll
        for (int i = 0; i < 4; ++i)
            af[i] = *(const short8*)&Alds[buf][(wr * 64 + i * 16 + ln) * 40 + quad * 8];
        #pragma unroll
        for (int j = 0; j < 4; ++j) {
            short8 bf = *(const short8*)&Blds[buf][(wc * 64 + j * 16 + ln) * 32 + quad * 8];
            #pragma unroll
            for (int i = 0; i < 4; ++i)
                acc[i][j] = __builtin_amdgcn_mfma_f32_16x16x32_bf16(af[i], bf, acc[i][j], 0, 0, 0);
        }
        if (more) {
            short8 w0, w1;
            w0[0]=(short)f2bf(fa0.x); w0[1]=(short)f2bf(fa0.y); w0[2]=(short)f2bf(fa0.z); w0[3]=(short)f2bf(fa0.w);
            w0[4]=(short)f2bf(fa1.x); w0[5]=(short)f2bf(fa1.y); w0[6]=(short)f2bf(fa1.z); w0[7]=(short)f2bf(fa1.w);
            w1[0]=(short)f2bf(fa2.x); w1[1]=(short)f2bf(fa2.y); w1[2]=(short)f2bf(fa2.z); w1[3]=(short)f2bf(fa2.w);
            w1[4]=(short)f2bf(fa3.x); w1[5]=(short)f2bf(fa3.y); w1[6]=(short)f2bf(fa3.z); w1[7]=(short)f2bf(fa3.w);
            *(short8*)&Alds[nxt][row * 40 + seg * 16]     = w0;
            *(short8*)&Alds[nxt][row * 40 + seg * 16 + 8] = w1;
        }
        __syncthreads();
    }

    float* dst = partial + (size_t)by * 3328 * 128;
    #pragma unroll
    for (int i = 0; i < 4; ++i) {
        #pragma unroll
        for (int j = 0; j < 4; ++j) {
            int rowb = m0 + wr * 64 + i * 16 + quad * 4;
            int col = wc * 64 + j * 16 + ln;
            #pragma unroll
            for (int r = 0; r < 4; ++r)
                dst[(size_t)(rowb + r) * 128 + col] = acc[i][j][r];
        }
    }
}

// ---------------------------------------------------------------- fused: ks-sum + tanh + mask -> xproj = xe @ gru_k + b_i
// blocks 0..199: 16 x-rows each (xe never hits global memory). block 200: ae rows.
__global__ __launch_bounds__(384) void xproj_fused(const float* __restrict__ partial,
                                                   const float* __restrict__ gru_k,
                                                   const float* __restrict__ b_i,
                                                   float* __restrict__ xproj,
                                                   float* __restrict__ maskg,
                                                   float* __restrict__ ae,
                                                   int ks) {
    const size_t SL = (size_t)3328 * 128;          // slice stride (floats)
    int tid = threadIdx.x;
    if (blockIdx.x == 200) {                       // a-embedding rows 3200..3231
        for (int i = tid; i < 32 * 128; i += 384) {
            float s = 0.f;
            for (int k = 0; k < ks; ++k) s += partial[(size_t)k * SL + 3200 * 128 + i];
            ae[i] = fast_tanh(s);
        }
        return;
    }
    __shared__ float xs[16 * 128];
    __shared__ int anyr[16];
    int row0 = blockIdx.x * 16;
    if (tid < 16) anyr[tid] = 0;
    __syncthreads();
    const float4v* p4 = (const float4v*)partial + (size_t)row0 * 32;  // 32 float4 per row
    const size_t SL4 = SL / 4;
    for (int i4 = tid; i4 < 512; i4 += 384) {
        float4v s = p4[i4];
        for (int k = 1; k < ks; ++k) {
            float4v t = p4[(size_t)k * SL4 + i4];
            s.x += t.x; s.y += t.y; s.z += t.z; s.w += t.w;
        }
        float4v v;
        v.x = fast_tanh(s.x); v.y = fast_tanh(s.y);
        v.z = fast_tanh(s.z); v.w = fast_tanh(s.w);
        *(float4v*)&xs[i4 * 4] = v;
        if (v.x != 0.f || v.y != 0.f || v.z != 0.f || v.w != 0.f)
            anyr[i4 >> 5] = 1;                     // benign race: all writers store 1
    }
    __syncthreads();
    if (tid < 16) maskg[row0 + tid] = anyr[tid] ? 1.f : 0.f;

    int j = tid;  // 0..383
    float acc[16];
    #pragma unroll
    for (int r = 0; r < 16; ++r) acc[r] = 0.f;
    float bi = b_i[j];
    for (int k4 = 0; k4 < 32; ++k4) {
        float g0 = gru_k[(k4 * 4 + 0) * 384 + j];
        float g1 = gru_k[(k4 * 4 + 1) * 384 + j];
        float g2 = gru_k[(k4 * 4 + 2) * 384 + j];
        float g3 = gru_k[(k4 * 4 + 3) * 384 + j];
        #pragma unroll
        for (int r = 0; r < 16; ++r) {
            float4v xv = *(const float4v*)&xs[r * 128 + k4 * 4];
            acc[r] = fmaf(xv.x, g0, acc[r]);
            acc[r] = fmaf(xv.y, g1, acc[r]);
            acc[r] = fmaf(xv.z, g2, acc[r]);
            acc[r] = fmaf(xv.w, g3, acc[r]);
        }
    }
    #pragma unroll
    for (int r = 0; r < 16; ++r)
        xproj[(size_t)(row0 + r) * 384 + j] = acc[r] + bi;
}

// ---------------------------------------------------------------- GRU scan + fused head: 1 block / batch
__global__ __launch_bounds__(384) void gru_fused(const float* __restrict__ xproj,
                                                 const float* __restrict__ maskg,
                                                 const float* __restrict__ gru_rk,
                                                 const float* __restrict__ b_r,
                                                 const float* __restrict__ ae,
                                                 const float* __restrict__ d,
                                                 const float* __restrict__ W1,
                                                 const float* __restrict__ b1,
                                                 const float* __restrict__ W2,
                                                 const float* __restrict__ b2,
                                                 float* __restrict__ out) {
    int b = blockIdx.x;
    int j = threadIdx.x;  // 0..383
    float w[128];
    #pragma unroll
    for (int k = 0; k < 128; ++k) w[k] = gru_rk[k * 384 + j];
    float br = b_r[j];
    __shared__ float4v hs4[32];
    __shared__ float recs[384];
    float* hs = (float*)hs4;
    float hreg = 0.f;
    if (j < 128) hs[j] = 0.f;
    const float* xp_base = xproj + (size_t)b * 100 * 384;
    const float* mk = maskg + b * 100;
    // prefetched gate inputs for j<128 threads
    float xz = 0.f, xr = 0.f, xh = 0.f;
    if (j < 128) { xz = xp_base[j]; xr = xp_base[128 + j]; xh = xp_base[256 + j]; }
    __syncthreads();
    for (int t = 0; t < 100; ++t) {
        // prefetch next step's gate inputs (latency hidden behind matvec + gates)
        float nxz = 0.f, nxr = 0.f, nxh = 0.f;
        if (t < 99 && j < 128) {
            const float* nb = xp_base + (t + 1) * 384;
            nxz = nb[j]; nxr = nb[128 + j]; nxh = nb[256 + j];
        }
        float s0 = 0.f, s1 = 0.f, s2 = 0.f, s3 = 0.f;
        #pragma unroll
        for (int k4 = 0; k4 < 32; ++k4) {
            float4v hv = hs4[k4];
            s0 = fmaf(hv.x, w[k4 * 4 + 0], s0);
            s1 = fmaf(hv.y, w[k4 * 4 + 1], s1);
            s2 = fmaf(hv.z, w[k4 * 4 + 2], s2);
            s3 = fmaf(hv.w, w[k4 * 4 + 3], s3);
        }
        recs[j] = br + ((s0 + s1) + (s2 + s3));
        __syncthreads();
        if (j < 128) {
            float z = sigmoidf_(xz + recs[j]);
            float r = sigmoidf_(xr + recs[128 + j]);
            float hh = fast_tanh(xh + r * recs[256 + j]);
            float hn = z * hreg + (1.f - z) * hh;
            hreg = (mk[t] != 0.f) ? hn : hreg;
            hs[j] = hreg;
        }
        __syncthreads();
        xz = nxz; xr = nxr; xh = nxh;
    }
    // ---- fused head: h is complete in hs[] after the final barrier
    if (j < 64) {
        int m = j;
        float s = b1[m];
        const float* ab = ae + b * 128;
        #pragma unroll 4
        for (int k = 0; k < 128; ++k) s = fmaf(hs[k], W1[k * 64 + m], s);
        #pragma unroll 4
        for (int k = 0; k < 128; ++k) s = fmaf(ab[k], W1[(128 + k) * 64 + m], s);
        float c = fast_tanh(s);
        float p = c * W2[m];
        #pragma unroll
        for (int off = 32; off > 0; off >>= 1) p += __shfl_down(p, off);
        if (m == 0) {
            p += d[b * 2 + 0] * W2[64] + d[b * 2 + 1] * W2[65] + b2[0];
            out[b] = sigmoidf_(p);
        }
    }
}

extern "C" void kernel_launch(void* const* d_in, const int* in_sizes, int n_in,
                              void* d_out, int out_size, void* d_ws, size_t ws_size,
                              hipStream_t stream) {
    (void)in_sizes; (void)n_in; (void)out_size;
    const float* x      = (const float*)d_in[0];
    const float* a      = (const float*)d_in[1];
    const float* d      = (const float*)d_in[2];
    const float* emb    = (const float*)d_in[3];
    const float* gru_k  = (const float*)d_in[4];
    const float* gru_rk = (const float*)d_in[5];
    const float* gbi    = (const float*)d_in[6];
    const float* gbr    = (const float*)d_in[7];
    const float* W1     = (const float*)d_in[8];
    const float* b1     = (const float*)d_in[9];
    const float* W2     = (const float*)d_in[10];
    const float* b2     = (const float*)d_in[11];
    float* out = (float*)d_out;

    char* ws = (char*)d_ws;
    unsigned short* embT = (unsigned short*)(ws);              //  5,120,000 B
    const size_t slice = (size_t)3328 * 128 * 4;               //  1,703,936 B
    float* partial = (float*)(ws + 5120000);

    // split-K slices: 16 preferred (416 blocks, 27 MB partial); shrink if ws is tight
    int ks = 16;
    {
        size_t fixed_rest = 16384 + 12800 + 4915200;           // ae + maskg + xproj
        while (ks > 1 && 5120000 + (size_t)ks * slice + fixed_rest > ws_size) ks >>= 1;
    }
    char* after = ws + 5120000 + (size_t)ks * slice;
    float* ae      = (float*)(after);                          //     16,384 B
    float* maskg   = (float*)(after + 16384);                  //     12,800 B
    float* xproj   = (float*)(after + 29184);                  //  4,915,200 B

    hipLaunchKernelGGL(cvt_embT,    dim3(313),    dim3(256), 0, stream, emb, embT);
    hipLaunchKernelGGL(big_gemm,    dim3(26, ks), dim3(256), 0, stream, x, a, embT, partial, ks);
    hipLaunchKernelGGL(xproj_fused, dim3(201),    dim3(384), 0, stream, partial, gru_k, gbi, xproj, maskg, ae, ks);
    hipLaunchKernelGGL(gru_fused,   dim3(32),     dim3(384), 0, stream, xproj, maskg, gru_rk, gbr,
                       ae, d, W1, b1, W2, b2, out);
}

// Round 4
// 543.280 us; speedup vs baseline: 1.0555x; 1.0397x over previous
//
#include <hip/hip_runtime.h>

typedef __attribute__((ext_vector_type(8))) short short8;
typedef __attribute__((ext_vector_type(4))) float float4v;
typedef __attribute__((ext_vector_type(2))) float float2v;

#define V_ 20000

__device__ __forceinline__ unsigned short f2bf(float f) {
    union { float f; unsigned int u; } v; v.f = f;
    unsigned int u = v.u;
    u += 0x7fffu + ((u >> 16) & 1u);
    return (unsigned short)(u >> 16);
}

__device__ __forceinline__ float fast_tanh(float x) {
    float xc = fminf(15.f, fmaxf(-15.f, x));
    float e = __expf(2.f * xc);
    return (e - 1.f) / (e + 1.f);   // tanh(0) == 0 exactly (mask depends on it)
}

__device__ __forceinline__ float sigmoidf_(float x) {
    float xc = fminf(30.f, fmaxf(-30.f, x));
    return 1.f / (1.f + __expf(-xc));
}

#define GLL16(gp, lp) __builtin_amdgcn_global_load_lds( \
    (const __attribute__((address_space(1))) void*)(gp), \
    (__attribute__((address_space(3))) void*)(lp), 16, 0, 0)

// ---------------------------------------------------------------- cvt emb -> bf16 transposed [128n][20000k]
__global__ __launch_bounds__(256) void cvt_embT(const float* __restrict__ emb,
                                                unsigned short* __restrict__ embT) {
    __shared__ unsigned short tile[128 * 65];
    int tid = threadIdx.x;
    int k0 = blockIdx.x * 64;
    const float4v* e4 = (const float4v*)emb;
    #pragma unroll
    for (int c = 0; c < 8; ++c) {
        int l4 = c * 256 + tid;      // float4 index in 64k x 128n tile
        int k = l4 >> 5;             // 32 float4 per k-row
        int n4 = l4 & 31;
        float4v f = {0.f, 0.f, 0.f, 0.f};
        if (k0 + k < V_) f = e4[(size_t)(k0 + k) * 32 + n4];
        tile[(n4 * 4 + 0) * 65 + k] = f2bf(f.x);
        tile[(n4 * 4 + 1) * 65 + k] = f2bf(f.y);
        tile[(n4 * 4 + 2) * 65 + k] = f2bf(f.z);
        tile[(n4 * 4 + 3) * 65 + k] = f2bf(f.w);
    }
    __syncthreads();
    #pragma unroll
    for (int c = 0; c < 4; ++c) {
        int l8 = c * 256 + tid;      // n*8 + seg
        int n = l8 >> 3, seg = l8 & 7;
        int kk = k0 + seg * 8;
        if (kk < V_) {
            short8 v;
            #pragma unroll
            for (int i = 0; i < 8; ++i) v[i] = (short)tile[n * 65 + seg * 8 + i];
            *(short8*)(embT + (size_t)n * V_ + kk) = v;
        }
    }
}

// ---------------------------------------------------------------- big GEMM: partial[ks][3328][128] = rows @ emb
// rows 0..3199 = x, 3200..3231 = a, rest padding. Double-buffered LDS,
// B staged via global_load_lds DMA (unpadded layout), A prefetched in regs.
// Plain coalesced stores per K-slice (NO atomics: ks=32 atomics cost ~35 us in
// round 1 — 13.6M L2 atomic ops; compact partial round-trip is LLC-resident).
__global__ __launch_bounds__(256, 4) void big_gemm(const float* __restrict__ x,
                                                   const float* __restrict__ a,
                                                   const unsigned short* __restrict__ embT,
                                                   float* __restrict__ partial,
                                                   int ks) {
    __shared__ unsigned short Alds[2][128 * 40];   // bf16, padded stride 40
    __shared__ unsigned short Blds[2][128 * 32];   // bf16, unpadded (DMA target)
    int tid = threadIdx.x;
    int bx = blockIdx.x, by = blockIdx.y;
    int m0 = bx * 128;
    int per = 625 / ks, extra = 625 % ks;
    int kb0 = by * per + (by < extra ? by : extra);
    int nkb = per + (by < extra ? 1 : 0);

    int lane = tid & 63, wave = tid >> 6;
    int wr = wave >> 1, wc = wave & 1;
    int ln = lane & 15, quad = lane >> 4;

    float4v acc[4][4];
    #pragma unroll
    for (int i = 0; i < 4; ++i)
        #pragma unroll
        for (int j = 0; j < 4; ++j) acc[i][j] = (float4v){0.f, 0.f, 0.f, 0.f};

    int row = tid >> 1, seg = tid & 1;
    int rg = m0 + row;
    int aidx = rg - 3200; aidx = aidx < 0 ? 0 : (aidx > 31 ? 31 : aidx);
    const float* __restrict__ srcA = (rg < 3200) ? (x + (size_t)rg * V_)
                                                 : (a + (size_t)aidx * V_);
    // B DMA mapping: call q in {0,1}: chunk c = q*256 + tid; brow=c>>2, bkq=c&3
    int brow0 = tid >> 2, bkq = tid & 3;
    int wbase = tid & ~63;                     // wave-uniform chunk base (q=0)
    const unsigned short* gB0 = embT + (size_t)brow0 * V_ + bkq * 8;
    const unsigned short* gB1 = embT + (size_t)(64 + brow0) * V_ + bkq * 8;

    float4v fa0, fa1, fa2, fa3;

    // ---- prologue: stage tile 0 into buf 0
    {
        int k0 = kb0 * 32;
        const float4v* ap = (const float4v*)(srcA + k0 + seg * 16);
        fa0 = ap[0]; fa1 = ap[1]; fa2 = ap[2]; fa3 = ap[3];
        GLL16(gB0 + k0, &Blds[0][(size_t)wbase * 8]);
        GLL16(gB1 + k0, &Blds[0][(size_t)(256 + wbase) * 8]);
        short8 w0, w1;
        w0[0]=(short)f2bf(fa0.x); w0[1]=(short)f2bf(fa0.y); w0[2]=(short)f2bf(fa0.z); w0[3]=(short)f2bf(fa0.w);
        w0[4]=(short)f2bf(fa1.x); w0[5]=(short)f2bf(fa1.y); w0[6]=(short)f2bf(fa1.z); w0[7]=(short)f2bf(fa1.w);
        w1[0]=(short)f2bf(fa2.x); w1[1]=(short)f2bf(fa2.y); w1[2]=(short)f2bf(fa2.z); w1[3]=(short)f2bf(fa2.w);
        w1[4]=(short)f2bf(fa3.x); w1[5]=(short)f2bf(fa3.y); w1[6]=(short)f2bf(fa3.z); w1[7]=(short)f2bf(fa3.w);
        *(short8*)&Alds[0][row * 40 + seg * 16]     = w0;
        *(short8*)&Alds[0][row * 40 + seg * 16 + 8] = w1;
    }
    __syncthreads();

    for (int it = 0; it < nkb; ++it) {
        int buf = it & 1, nxt = buf ^ 1;
        bool more = (it + 1 < nkb);
        if (more) {
            int k0 = (kb0 + it + 1) * 32;
            const float4v* ap = (const float4v*)(srcA + k0 + seg * 16);
            fa0 = ap[0]; fa1 = ap[1]; fa2 = ap[2]; fa3 = ap[3];
            GLL16(gB0 + k0, &Blds[nxt][(size_t)wbase * 8]);
            GLL16(gB1 + k0, &Blds[nxt][(size_t)(256 + wbase) * 8]);
        }
        short8 af[4];
        #pragma unroll
        for (int i = 0; i < 4; ++i)
            af[i] = *(const short8*)&Alds[buf][(wr * 64 + i * 16 + ln) * 40 + quad * 8];
        #pragma unroll
        for (int j = 0; j < 4; ++j) {
            short8 bf = *(const short8*)&Blds[buf][(wc * 64 + j * 16 + ln) * 32 + quad * 8];
            #pragma unroll
            for (int i = 0; i < 4; ++i)
                acc[i][j] = __builtin_amdgcn_mfma_f32_16x16x32_bf16(af[i], bf, acc[i][j], 0, 0, 0);
        }
        if (more) {
            short8 w0, w1;
            w0[0]=(short)f2bf(fa0.x); w0[1]=(short)f2bf(fa0.y); w0[2]=(short)f2bf(fa0.z); w0[3]=(short)f2bf(fa0.w);
            w0[4]=(short)f2bf(fa1.x); w0[5]=(short)f2bf(fa1.y); w0[6]=(short)f2bf(fa1.z); w0[7]=(short)f2bf(fa1.w);
            w1[0]=(short)f2bf(fa2.x); w1[1]=(short)f2bf(fa2.y); w1[2]=(short)f2bf(fa2.z); w1[3]=(short)f2bf(fa2.w);
            w1[4]=(short)f2bf(fa3.x); w1[5]=(short)f2bf(fa3.y); w1[6]=(short)f2bf(fa3.z); w1[7]=(short)f2bf(fa3.w);
            *(short8*)&Alds[nxt][row * 40 + seg * 16]     = w0;
            *(short8*)&Alds[nxt][row * 40 + seg * 16 + 8] = w1;
        }
        __syncthreads();
    }

    float* dst = partial + (size_t)by * 3328 * 128;
    #pragma unroll
    for (int i = 0; i < 4; ++i) {
        #pragma unroll
        for (int j = 0; j < 4; ++j) {
            int rowb = m0 + wr * 64 + i * 16 + quad * 4;
            int col = wc * 64 + j * 16 + ln;
            #pragma unroll
            for (int r = 0; r < 4; ++r)
                dst[(size_t)(rowb + r) * 128 + col] = acc[i][j][r];
        }
    }
}

// ---------------------------------------------------------------- fused: ks-sum + tanh + mask -> xproj = xe @ gru_k + b_i
// blocks 0..199: 16 x-rows each (xe never hits global memory). block 200: ae rows.
// Inner product uses packed-f32 FMA (v_pk_fma_f32 via v2f32 fma) — halves VALU issue.
__global__ __launch_bounds__(384) void xproj_fused(const float* __restrict__ partial,
                                                   const float* __restrict__ gru_k,
                                                   const float* __restrict__ b_i,
                                                   float* __restrict__ xproj,
                                                   float* __restrict__ maskg,
                                                   float* __restrict__ ae,
                                                   int ks) {
    const size_t SL = (size_t)3328 * 128;          // slice stride (floats)
    int tid = threadIdx.x;
    if (blockIdx.x == 200) {                       // a-embedding rows 3200..3231
        for (int i = tid; i < 32 * 128; i += 384) {
            float s = 0.f;
            for (int k = 0; k < ks; ++k) s += partial[(size_t)k * SL + 3200 * 128 + i];
            ae[i] = fast_tanh(s);
        }
        return;
    }
    __shared__ float xs[16 * 128];
    __shared__ int anyr[16];
    int row0 = blockIdx.x * 16;
    if (tid < 16) anyr[tid] = 0;
    __syncthreads();
    const float4v* p4 = (const float4v*)partial + (size_t)row0 * 32;  // 32 float4 per row
    const size_t SL4 = SL / 4;
    for (int i4 = tid; i4 < 512; i4 += 384) {
        float4v s = p4[i4];
        for (int k = 1; k < ks; ++k) {
            float4v t = p4[(size_t)k * SL4 + i4];
            s.x += t.x; s.y += t.y; s.z += t.z; s.w += t.w;
        }
        float4v v;
        v.x = fast_tanh(s.x); v.y = fast_tanh(s.y);
        v.z = fast_tanh(s.z); v.w = fast_tanh(s.w);
        *(float4v*)&xs[i4 * 4] = v;
        if (v.x != 0.f || v.y != 0.f || v.z != 0.f || v.w != 0.f)
            anyr[i4 >> 5] = 1;                     // benign race: all writers store 1
    }
    __syncthreads();
    if (tid < 16) maskg[row0 + tid] = anyr[tid] ? 1.f : 0.f;

    int j = tid;  // 0..383
    float2v acc[16];
    #pragma unroll
    for (int r = 0; r < 16; ++r) acc[r] = (float2v){0.f, 0.f};
    float bi = b_i[j];
    for (int k4 = 0; k4 < 32; ++k4) {
        float2v g01 = { gru_k[(k4 * 4 + 0) * 384 + j], gru_k[(k4 * 4 + 1) * 384 + j] };
        float2v g23 = { gru_k[(k4 * 4 + 2) * 384 + j], gru_k[(k4 * 4 + 3) * 384 + j] };
        #pragma unroll
        for (int r = 0; r < 16; ++r) {
            float4v xv = *(const float4v*)&xs[r * 128 + k4 * 4];
            float2v x01 = {xv.x, xv.y}, x23 = {xv.z, xv.w};
            acc[r] = __builtin_elementwise_fma(x01, g01, acc[r]);
            acc[r] = __builtin_elementwise_fma(x23, g23, acc[r]);
        }
    }
    #pragma unroll
    for (int r = 0; r < 16; ++r)
        xproj[(size_t)(row0 + r) * 384 + j] = (acc[r].x + acc[r].y) + bi;
}

// ---------------------------------------------------------------- GRU scan + fused head: 1 block / batch
// Packed-f32 FMA matvec (half the issue cycles) + exact tail-trim: mask is
// contiguous-trailing (x rows zeroed for t>=len), masked steps are identity.
__global__ __launch_bounds__(384) void gru_fused(const float* __restrict__ xproj,
                                                 const float* __restrict__ maskg,
                                                 const float* __restrict__ gru_rk,
                                                 const float* __restrict__ b_r,
                                                 const float* __restrict__ ae,
                                                 const float* __restrict__ d,
                                                 const float* __restrict__ W1,
                                                 const float* __restrict__ b1,
                                                 const float* __restrict__ W2,
                                                 const float* __restrict__ b2,
                                                 float* __restrict__ out) {
    int b = blockIdx.x;
    int j = threadIdx.x;  // 0..383
    float2v wv[64];       // wv[i] = {rk[2i][j], rk[2i+1][j]}
    #pragma unroll
    for (int i = 0; i < 64; ++i) {
        wv[i] = (float2v){ gru_rk[(2 * i) * 384 + j], gru_rk[(2 * i + 1) * 384 + j] };
    }
    float br = b_r[j];
    __shared__ float4v hs4[32];
    __shared__ float recs[384];
    __shared__ int ntS;
    float* hs = (float*)hs4;
    float hreg = 0.f;
    if (j == 0) ntS = 0;
    if (j < 128) hs[j] = 0.f;
    const float* xp_base = xproj + (size_t)b * 100 * 384;
    const float* mk = maskg + b * 100;
    // prefetched gate inputs for j<128 threads
    float xz = 0.f, xr = 0.f, xh = 0.f;
    if (j < 128) { xz = xp_base[j]; xr = xp_base[128 + j]; xh = xp_base[256 + j]; }
    __syncthreads();
    if (j < 100 && mk[j] != 0.f) atomicMax(&ntS, j + 1);
    __syncthreads();
    int nt = ntS;         // steps t>=nt have mask 0 -> h unchanged (exact skip)
    for (int t = 0; t < nt; ++t) {
        // prefetch next step's gate inputs (latency hidden behind matvec + gates)
        float nxz = 0.f, nxr = 0.f, nxh = 0.f;
        if (t + 1 < nt && j < 128) {
            const float* nb = xp_base + (t + 1) * 384;
            nxz = nb[j]; nxr = nb[128 + j]; nxh = nb[256 + j];
        }
        float2v a0 = {0.f, 0.f}, a1 = {0.f, 0.f}, a2 = {0.f, 0.f}, a3 = {0.f, 0.f};
        #pragma unroll
        for (int k4 = 0; k4 < 32; k4 += 2) {
            float4v hA = hs4[k4], hB = hs4[k4 + 1];
            float2v hA0 = {hA.x, hA.y}, hA1 = {hA.z, hA.w};
            float2v hB0 = {hB.x, hB.y}, hB1 = {hB.z, hB.w};
            a0 = __builtin_elementwise_fma(hA0, wv[2 * k4 + 0], a0);
            a1 = __builtin_elementwise_fma(hA1, wv[2 * k4 + 1], a1);
            a2 = __builtin_elementwise_fma(hB0, wv[2 * k4 + 2], a2);
            a3 = __builtin_elementwise_fma(hB1, wv[2 * k4 + 3], a3);
        }
        recs[j] = br + (((a0.x + a0.y) + (a1.x + a1.y)) + ((a2.x + a2.y) + (a3.x + a3.y)));
        __syncthreads();
        if (j < 128) {
            float z = sigmoidf_(xz + recs[j]);
            float r = sigmoidf_(xr + recs[128 + j]);
            float hh = fast_tanh(xh + r * recs[256 + j]);
            float hn = z * hreg + (1.f - z) * hh;
            hreg = (mk[t] != 0.f) ? hn : hreg;
            hs[j] = hreg;
        }
        __syncthreads();
        xz = nxz; xr = nxr; xh = nxh;
    }
    // ---- fused head: h is complete in hs[] after the final barrier
    if (j < 64) {
        int m = j;
        float s = b1[m];
        const float* ab = ae + b * 128;
        #pragma unroll 4
        for (int k = 0; k < 128; ++k) s = fmaf(hs[k], W1[k * 64 + m], s);
        #pragma unroll 4
        for (int k = 0; k < 128; ++k) s = fmaf(ab[k], W1[(128 + k) * 64 + m], s);
        float c = fast_tanh(s);
        float p = c * W2[m];
        #pragma unroll
        for (int off = 32; off > 0; off >>= 1) p += __shfl_down(p, off);
        if (m == 0) {
            p += d[b * 2 + 0] * W2[64] + d[b * 2 + 1] * W2[65] + b2[0];
            out[b] = sigmoidf_(p);
        }
    }
}

extern "C" void kernel_launch(void* const* d_in, const int* in_sizes, int n_in,
                              void* d_out, int out_size, void* d_ws, size_t ws_size,
                              hipStream_t stream) {
    (void)in_sizes; (void)n_in; (void)out_size;
    const float* x      = (const float*)d_in[0];
    const float* a      = (const float*)d_in[1];
    const float* d      = (const float*)d_in[2];
    const float* emb    = (const float*)d_in[3];
    const float* gru_k  = (const float*)d_in[4];
    const float* gru_rk = (const float*)d_in[5];
    const float* gbi    = (const float*)d_in[6];
    const float* gbr    = (const float*)d_in[7];
    const float* W1     = (const float*)d_in[8];
    const float* b1     = (const float*)d_in[9];
    const float* W2     = (const float*)d_in[10];
    const float* b2     = (const float*)d_in[11];
    float* out = (float*)d_out;

    char* ws = (char*)d_ws;
    unsigned short* embT = (unsigned short*)(ws);              //  5,120,000 B
    const size_t slice = (size_t)3328 * 128 * 4;               //  1,703,936 B
    float* partial = (float*)(ws + 5120000);

    // split-K slices: 16 preferred (416 blocks, 27 MB partial); shrink if ws is tight
    int ks = 16;
    {
        size_t fixed_rest = 16384 + 12800 + 4915200;           // ae + maskg + xproj
        while (ks > 1 && 5120000 + (size_t)ks * slice + fixed_rest > ws_size) ks >>= 1;
    }
    char* after = ws + 5120000 + (size_t)ks * slice;
    float* ae      = (float*)(after);                          //     16,384 B
    float* maskg   = (float*)(after + 16384);                  //     12,800 B
    float* xproj   = (float*)(after + 29184);                  //  4,915,200 B

    hipLaunchKernelGGL(cvt_embT,    dim3(313),    dim3(256), 0, stream, emb, embT);
    hipLaunchKernelGGL(big_gemm,    dim3(26, ks), dim3(256), 0, stream, x, a, embT, partial, ks);
    hipLaunchKernelGGL(xproj_fused, dim3(201),    dim3(384), 0, stream, partial, gru_k, gbi, xproj, maskg, ae, ks);
    hipLaunchKernelGGL(gru_fused,   dim3(32),     dim3(384), 0, stream, xproj, maskg, gru_rk, gbr,
                       ae, d, W1, b1, W2, b2, out);
}

// Round 6
// 531.909 us; speedup vs baseline: 1.0780x; 1.0214x over previous
//
#include <hip/hip_runtime.h>

typedef __attribute__((ext_vector_type(8))) short short8;
typedef __attribute__((ext_vector_type(4))) float float4v;
typedef __attribute__((ext_vector_type(2))) float float2v;

#define V_ 20000

__device__ __forceinline__ unsigned short f2bf(float f) {
    union { float f; unsigned int u; } v; v.f = f;
    unsigned int u = v.u;
    u += 0x7fffu + ((u >> 16) & 1u);
    return (unsigned short)(u >> 16);
}

__device__ __forceinline__ float fast_tanh(float x) {
    float xc = fminf(15.f, fmaxf(-15.f, x));
    float e = __expf(2.f * xc);
    return (e - 1.f) / (e + 1.f);   // tanh(0) == 0 exactly (mask depends on it)
}

__device__ __forceinline__ float sigmoidf_(float x) {
    float xc = fminf(30.f, fmaxf(-30.f, x));
    return 1.f / (1.f + __expf(-xc));
}

#define GLL16(gp, lp) __builtin_amdgcn_global_load_lds( \
    (const __attribute__((address_space(1))) void*)(gp), \
    (__attribute__((address_space(3))) void*)(lp), 16, 0, 0)

// ---------------------------------------------------------------- cvt emb -> bf16 transposed [128n][20000k]
__global__ __launch_bounds__(256) void cvt_embT(const float* __restrict__ emb,
                                                unsigned short* __restrict__ embT) {
    __shared__ unsigned short tile[128 * 65];
    int tid = threadIdx.x;
    int k0 = blockIdx.x * 64;
    const float4v* e4 = (const float4v*)emb;
    #pragma unroll
    for (int c = 0; c < 8; ++c) {
        int l4 = c * 256 + tid;      // float4 index in 64k x 128n tile
        int k = l4 >> 5;             // 32 float4 per k-row
        int n4 = l4 & 31;
        float4v f = {0.f, 0.f, 0.f, 0.f};
        if (k0 + k < V_) f = e4[(size_t)(k0 + k) * 32 + n4];
        tile[(n4 * 4 + 0) * 65 + k] = f2bf(f.x);
        tile[(n4 * 4 + 1) * 65 + k] = f2bf(f.y);
        tile[(n4 * 4 + 2) * 65 + k] = f2bf(f.z);
        tile[(n4 * 4 + 3) * 65 + k] = f2bf(f.w);
    }
    __syncthreads();
    #pragma unroll
    for (int c = 0; c < 4; ++c) {
        int l8 = c * 256 + tid;      // n*8 + seg
        int n = l8 >> 3, seg = l8 & 7;
        int kk = k0 + seg * 8;
        if (kk < V_) {
            short8 v;
            #pragma unroll
            for (int i = 0; i < 8; ++i) v[i] = (short)tile[n * 65 + seg * 8 + i];
            *(short8*)(embT + (size_t)n * V_ + kk) = v;
        }
    }
}

// ---------------------------------------------------------------- big GEMM: partial[ks][3328][128] = rows @ emb
// BM=64 tile (round 5: halves partial footprint at ks=8, doubles per-block
// K-length to 78 iters). rows 0..3199 = x, 3200..3231 = a, rest padding.
// Double-buffered LDS, B staged via global_load_lds DMA, A prefetched in regs.
// Plain stores (NO atomics — round-1 showed ks*full-size atomics cost ~35 us).
__global__ __launch_bounds__(256, 4) void big_gemm(const float* __restrict__ x,
                                                   const float* __restrict__ a,
                                                   const unsigned short* __restrict__ embT,
                                                   float* __restrict__ partial,
                                                   int ks) {
    __shared__ unsigned short Alds[2][64 * 40];    // bf16, padded stride 40
    __shared__ unsigned short Blds[2][128 * 32];   // bf16, unpadded (DMA target)
    int tid = threadIdx.x;
    int bx = blockIdx.x, by = blockIdx.y;
    int m0 = bx * 64;
    int per = 625 / ks, extra = 625 % ks;
    int kb0 = by * per + (by < extra ? by : extra);
    int nkb = per + (by < extra ? 1 : 0);

    int lane = tid & 63, wave = tid >> 6;
    int wr = wave >> 1, wc = wave & 1;             // wave-tile: 32 rows x 64 cols
    int ln = lane & 15, quad = lane >> 4;

    float4v acc[2][4];
    #pragma unroll
    for (int i = 0; i < 2; ++i)
        #pragma unroll
        for (int j = 0; j < 4; ++j) acc[i][j] = (float4v){0.f, 0.f, 0.f, 0.f};

    int row = tid >> 2, kseg = tid & 3;            // 64 rows x 4 k-segments (8 floats each)
    int rg = m0 + row;
    int aidx = rg - 3200; aidx = aidx < 0 ? 0 : (aidx > 31 ? 31 : aidx);
    const float* __restrict__ srcA = (rg < 3200) ? (x + (size_t)rg * V_)
                                                 : (a + (size_t)aidx * V_);
    // B DMA mapping: call q in {0,1}: chunk c = q*256 + tid; brow=c>>2, bkq=c&3
    int brow0 = tid >> 2, bkq = tid & 3;
    int wbase = tid & ~63;                     // wave-uniform chunk base (q=0)
    const unsigned short* gB0 = embT + (size_t)brow0 * V_ + bkq * 8;
    const unsigned short* gB1 = embT + (size_t)(64 + brow0) * V_ + bkq * 8;

    float4v fa0, fa1;

    // ---- prologue: stage tile 0 into buf 0
    {
        int k0 = kb0 * 32;
        const float4v* ap = (const float4v*)(srcA + k0 + kseg * 8);
        fa0 = ap[0]; fa1 = ap[1];
        GLL16(gB0 + k0, &Blds[0][(size_t)wbase * 8]);
        GLL16(gB1 + k0, &Blds[0][(size_t)(256 + wbase) * 8]);
        short8 w0;
        w0[0]=(short)f2bf(fa0.x); w0[1]=(short)f2bf(fa0.y); w0[2]=(short)f2bf(fa0.z); w0[3]=(short)f2bf(fa0.w);
        w0[4]=(short)f2bf(fa1.x); w0[5]=(short)f2bf(fa1.y); w0[6]=(short)f2bf(fa1.z); w0[7]=(short)f2bf(fa1.w);
        *(short8*)&Alds[0][row * 40 + kseg * 8] = w0;
    }
    __syncthreads();

    for (int it = 0; it < nkb; ++it) {
        int buf = it & 1, nxt = buf ^ 1;
        bool more = (it + 1 < nkb);
        if (more) {
            int k0 = (kb0 + it + 1) * 32;
            const float4v* ap = (const float4v*)(srcA + k0 + kseg * 8);
            fa0 = ap[0]; fa1 = ap[1];
            GLL16(gB0 + k0, &Blds[nxt][(size_t)wbase * 8]);
            GLL16(gB1 + k0, &Blds[nxt][(size_t)(256 + wbase) * 8]);
        }
        short8 af[2];
        #pragma unroll
        for (int i = 0; i < 2; ++i)
            af[i] = *(const short8*)&Alds[buf][(wr * 32 + i * 16 + ln) * 40 + quad * 8];
        #pragma unroll
        for (int j = 0; j < 4; ++j) {
            short8 bf = *(const short8*)&Blds[buf][(wc * 64 + j * 16 + ln) * 32 + quad * 8];
            #pragma unroll
            for (int i = 0; i < 2; ++i)
                acc[i][j] = __builtin_amdgcn_mfma_f32_16x16x32_bf16(af[i], bf, acc[i][j], 0, 0, 0);
        }
        if (more) {
            short8 w0;
            w0[0]=(short)f2bf(fa0.x); w0[1]=(short)f2bf(fa0.y); w0[2]=(short)f2bf(fa0.z); w0[3]=(short)f2bf(fa0.w);
            w0[4]=(short)f2bf(fa1.x); w0[5]=(short)f2bf(fa1.y); w0[6]=(short)f2bf(fa1.z); w0[7]=(short)f2bf(fa1.w);
            *(short8*)&Alds[nxt][row * 40 + kseg * 8] = w0;
        }
        __syncthreads();
    }

    float* dst = partial + (size_t)by * 3328 * 128;
    #pragma unroll
    for (int i = 0; i < 2; ++i) {
        #pragma unroll
        for (int j = 0; j < 4; ++j) {
            int rowb = m0 + wr * 32 + i * 16 + quad * 4;
            int col = wc * 64 + j * 16 + ln;
            #pragma unroll
            for (int r = 0; r < 4; ++r)
                dst[(size_t)(rowb + r) * 128 + col] = acc[i][j][r];
        }
    }
}

// ---------------------------------------------------------------- fused: ks-sum + tanh + mask -> xproj = xe @ gru_k + b_i
// blocks 0..199: 16 x-rows each. block 200: ae rows. blocks 201..216: LLC
// prewarm of gru_rk + W1 (gru's 32 blocks otherwise each pull 196 KB at
// per-CU HBM BW — prewarm makes those reads LLC hits).
__global__ __launch_bounds__(384) void xproj_fused(const float* __restrict__ partial,
                                                   const float* __restrict__ gru_k,
                                                   const float* __restrict__ b_i,
                                                   const float* __restrict__ gru_rk,
                                                   const float* __restrict__ W1,
                                                   float* __restrict__ xproj,
                                                   float* __restrict__ maskg,
                                                   float* __restrict__ ae,
                                                   int ks) {
    const size_t SL = (size_t)3328 * 128;          // slice stride (floats)
    int tid = threadIdx.x;
    if (blockIdx.x > 200) {                        // LLC prewarm (reads kept live)
        int pb = blockIdx.x - 201;                 // 0..15
        int idx = pb * 384 + tid;                  // 0..6143
        const float4v* rk4 = (const float4v*)gru_rk;   // 12288 float4
        float4v v1 = rk4[idx];
        float4v v2 = rk4[idx + 6144];
        float s = v1.x + v2.x;
        if (idx < 2080) { float4v v3 = ((const float4v*)W1)[idx]; s += v3.x; }
        asm volatile("" :: "v"(s));
        return;
    }
    if (blockIdx.x == 200) {                       // a-embedding rows 3200..3231
        for (int i = tid; i < 32 * 128; i += 384) {
            float s = 0.f;
            for (int k = 0; k < ks; ++k) s += partial[(size_t)k * SL + 3200 * 128 + i];
            ae[i] = fast_tanh(s);
        }
        return;
    }
    __shared__ float xs[16 * 128];
    __shared__ int anyr[16];
    int row0 = blockIdx.x * 16;
    if (tid < 16) anyr[tid] = 0;
    __syncthreads();
    const float4v* p4 = (const float4v*)partial + (size_t)row0 * 32;  // 32 float4 per row
    const size_t SL4 = SL / 4;
    for (int i4 = tid; i4 < 512; i4 += 384) {
        float4v s = p4[i4];
        for (int k = 1; k < ks; ++k) {
            float4v t = p4[(size_t)k * SL4 + i4];
            s.x += t.x; s.y += t.y; s.z += t.z; s.w += t.w;
        }
        float4v v;
        v.x = fast_tanh(s.x); v.y = fast_tanh(s.y);
        v.z = fast_tanh(s.z); v.w = fast_tanh(s.w);
        *(float4v*)&xs[i4 * 4] = v;
        if (v.x != 0.f || v.y != 0.f || v.z != 0.f || v.w != 0.f)
            anyr[i4 >> 5] = 1;                     // benign race: all writers store 1
    }
    __syncthreads();
    if (tid < 16) maskg[row0 + tid] = anyr[tid] ? 1.f : 0.f;

    int j = tid;  // 0..383
    float2v acc[16];
    #pragma unroll
    for (int r = 0; r < 16; ++r) acc[r] = (float2v){0.f, 0.f};
    float bi = b_i[j];
    for (int k4 = 0; k4 < 32; ++k4) {
        float2v g01 = { gru_k[(k4 * 4 + 0) * 384 + j], gru_k[(k4 * 4 + 1) * 384 + j] };
        float2v g23 = { gru_k[(k4 * 4 + 2) * 384 + j], gru_k[(k4 * 4 + 3) * 384 + j] };
        #pragma unroll
        for (int r = 0; r < 16; ++r) {
            float4v xv = *(const float4v*)&xs[r * 128 + k4 * 4];
            float2v x01 = {xv.x, xv.y}, x23 = {xv.z, xv.w};
            acc[r] = __builtin_elementwise_fma(x01, g01, acc[r]);
            acc[r] = __builtin_elementwise_fma(x23, g23, acc[r]);
        }
    }
    #pragma unroll
    for (int r = 0; r < 16; ++r)
        xproj[(size_t)(row0 + r) * 384 + j] = (acc[r].x + acc[r].y) + bi;
}

// ---------------------------------------------------------------- GRU scan + fused head: 1 block / batch
// Packed-f32 FMA matvec (half the issue cycles) + exact tail-trim: mask is
// contiguous-trailing (x rows zeroed for t>=len), masked steps are identity.
__global__ __launch_bounds__(384) void gru_fused(const float* __restrict__ xproj,
                                                 const float* __restrict__ maskg,
                                                 const float* __restrict__ gru_rk,
                                                 const float* __restrict__ b_r,
                                                 const float* __restrict__ ae,
                                                 const float* __restrict__ d,
                                                 const float* __restrict__ W1,
                                                 const float* __restrict__ b1,
                                                 const float* __restrict__ W2,
                                                 const float* __restrict__ b2,
                                                 float* __restrict__ out) {
    int b = blockIdx.x;
    int j = threadIdx.x;  // 0..383
    float2v wv[64];       // wv[i] = {rk[2i][j], rk[2i+1][j]}
    #pragma unroll
    for (int i = 0; i < 64; ++i) {
        wv[i] = (float2v){ gru_rk[(2 * i) * 384 + j], gru_rk[(2 * i + 1) * 384 + j] };
    }
    float br = b_r[j];
    __shared__ float4v hs4[32];
    __shared__ float recs[384];
    __shared__ int ntS;
    float* hs = (float*)hs4;
    float hreg = 0.f;
    if (j == 0) ntS = 0;
    if (j < 128) hs[j] = 0.f;
    const float* xp_base = xproj + (size_t)b * 100 * 384;
    const float* mk = maskg + b * 100;
    // prefetched gate inputs for j<128 threads
    float xz = 0.f, xr = 0.f, xh = 0.f;
    if (j < 128) { xz = xp_base[j]; xr = xp_base[128 + j]; xh = xp_base[256 + j]; }
    __syncthreads();
    if (j < 100 && mk[j] != 0.f) atomicMax(&ntS, j + 1);
    __syncthreads();
    int nt = ntS;         // steps t>=nt have mask 0 -> h unchanged (exact skip)
    for (int t = 0; t < nt; ++t) {
        // prefetch next step's gate inputs (latency hidden behind matvec + gates)
        float nxz = 0.f, nxr = 0.f, nxh = 0.f;
        if (t + 1 < nt && j < 128) {
            const float* nb = xp_base + (t + 1) * 384;
            nxz = nb[j]; nxr = nb[128 + j]; nxh = nb[256 + j];
        }
        float2v a0 = {0.f, 0.f}, a1 = {0.f, 0.f}, a2 = {0.f, 0.f}, a3 = {0.f, 0.f};
        #pragma unroll
        for (int k4 = 0; k4 < 32; k4 += 2) {
            float4v hA = hs4[k4], hB = hs4[k4 + 1];
            float2v hA0 = {hA.x, hA.y}, hA1 = {hA.z, hA.w};
            float2v hB0 = {hB.x, hB.y}, hB1 = {hB.z, hB.w};
            a0 = __builtin_elementwise_fma(hA0, wv[2 * k4 + 0], a0);
            a1 = __builtin_elementwise_fma(hA1, wv[2 * k4 + 1], a1);
            a2 = __builtin_elementwise_fma(hB0, wv[2 * k4 + 2], a2);
            a3 = __builtin_elementwise_fma(hB1, wv[2 * k4 + 3], a3);
        }
        recs[j] = br + (((a0.x + a0.y) + (a1.x + a1.y)) + ((a2.x + a2.y) + (a3.x + a3.y)));
        __syncthreads();
        if (j < 128) {
            float z = sigmoidf_(xz + recs[j]);
            float r = sigmoidf_(xr + recs[128 + j]);
            float hh = fast_tanh(xh + r * recs[256 + j]);
            float hn = z * hreg + (1.f - z) * hh;
            hreg = (mk[t] != 0.f) ? hn : hreg;
            hs[j] = hreg;
        }
        __syncthreads();
        xz = nxz; xr = nxr; xh = nxh;
    }
    // ---- fused head: h is complete in hs[] after the final barrier
    if (j < 64) {
        int m = j;
        float s = b1[m];
        const float* ab = ae + b * 128;
        #pragma unroll 4
        for (int k = 0; k < 128; ++k) s = fmaf(hs[k], W1[k * 64 + m], s);
        #pragma unroll 4
        for (int k = 0; k < 128; ++k) s = fmaf(ab[k], W1[(128 + k) * 64 + m], s);
        float c = fast_tanh(s);
        float p = c * W2[m];
        #pragma unroll
        for (int off = 32; off > 0; off >>= 1) p += __shfl_down(p, off);
        if (m == 0) {
            p += d[b * 2 + 0] * W2[64] + d[b * 2 + 1] * W2[65] + b2[0];
            out[b] = sigmoidf_(p);
        }
    }
}

extern "C" void kernel_launch(void* const* d_in, const int* in_sizes, int n_in,
                              void* d_out, int out_size, void* d_ws, size_t ws_size,
                              hipStream_t stream) {
    (void)in_sizes; (void)n_in; (void)out_size;
    const float* x      = (const float*)d_in[0];
    const float* a      = (const float*)d_in[1];
    const float* d      = (const float*)d_in[2];
    const float* emb    = (const float*)d_in[3];
    const float* gru_k  = (const float*)d_in[4];
    const float* gru_rk = (const float*)d_in[5];
    const float* gbi    = (const float*)d_in[6];
    const float* gbr    = (const float*)d_in[7];
    const float* W1     = (const float*)d_in[8];
    const float* b1     = (const float*)d_in[9];
    const float* W2     = (const float*)d_in[10];
    const float* b2     = (const float*)d_in[11];
    float* out = (float*)d_out;

    char* ws = (char*)d_ws;
    unsigned short* embT = (unsigned short*)(ws);              //  5,120,000 B
    const size_t slice = (size_t)3328 * 128 * 4;               //  1,703,936 B
    float* partial = (float*)(ws + 5120000);

    // split-K slices: 8 preferred (52x8 = 416 blocks, 13.6 MB partial)
    int ks = 8;
    {
        size_t fixed_rest = 16384 + 12800 + 4915200;           // ae + maskg + xproj
        while (ks > 1 && 5120000 + (size_t)ks * slice + fixed_rest > ws_size) ks >>= 1;
    }
    char* after = ws + 5120000 + (size_t)ks * slice;
    float* ae      = (float*)(after);                          //     16,384 B
    float* maskg   = (float*)(after + 16384);                  //     12,800 B
    float* xproj   = (float*)(after + 29184);                  //  4,915,200 B

    hipLaunchKernelGGL(cvt_embT,    dim3(313),    dim3(256), 0, stream, emb, embT);
    hipLaunchKernelGGL(big_gemm,    dim3(52, ks), dim3(256), 0, stream, x, a, embT, partial, ks);
    hipLaunchKernelGGL(xproj_fused, dim3(217),    dim3(384), 0, stream, partial, gru_k, gbi,
                       gru_rk, W1, xproj, maskg, ae, ks);
    hipLaunchKernelGGL(gru_fused,   dim3(32),     dim3(384), 0, stream, xproj, maskg, gru_rk, gbr,
                       ae, d, W1, b1, W2, b2, out);
}

// Round 9
// 531.581 us; speedup vs baseline: 1.0787x; 1.0006x over previous
//
#include <hip/hip_runtime.h>
#include <hip/hip_bf16.h>

typedef __attribute__((ext_vector_type(8))) short short8;
typedef __attribute__((ext_vector_type(4))) float float4v;
typedef __attribute__((ext_vector_type(2))) float float2v;

#define V_ 20000

// RNE f32->bf16 via compiler cast: hipcc fuses adjacent pairs into
// v_cvt_pk_bf16_f32 (1 inst / 2 elems) — the manual bit-twiddle version
// (~3-4 VALU/elem) can't be pattern-matched (m240: scalar cast > hand asm).
__device__ __forceinline__ unsigned short f2bf(float f) {
    union { __hip_bfloat16 h; unsigned short u; } v;
    v.h = __float2bfloat16(f);
    return v.u;
}

__device__ __forceinline__ float fast_tanh(float x) {
    float xc = fminf(15.f, fmaxf(-15.f, x));
    float e = __expf(2.f * xc);
    return (e - 1.f) / (e + 1.f);   // tanh(0) == 0 exactly (mask depends on it)
}

__device__ __forceinline__ float sigmoidf_(float x) {
    float xc = fminf(30.f, fmaxf(-30.f, x));
    return 1.f / (1.f + __expf(-xc));
}

#define GLL16(gp, lp) __builtin_amdgcn_global_load_lds( \
    (const __attribute__((address_space(1))) void*)(gp), \
    (__attribute__((address_space(3))) void*)(lp), 16, 0, 0)

// ---------------------------------------------------------------- cvt emb -> bf16 transposed [128n][20000k]
__global__ __launch_bounds__(256) void cvt_embT(const float* __restrict__ emb,
                                                unsigned short* __restrict__ embT) {
    __shared__ unsigned short tile[128 * 65];
    int tid = threadIdx.x;
    int k0 = blockIdx.x * 64;
    const float4v* e4 = (const float4v*)emb;
    #pragma unroll
    for (int c = 0; c < 8; ++c) {
        int l4 = c * 256 + tid;      // float4 index in 64k x 128n tile
        int k = l4 >> 5;             // 32 float4 per k-row
        int n4 = l4 & 31;
        float4v f = {0.f, 0.f, 0.f, 0.f};
        if (k0 + k < V_) f = __builtin_nontemporal_load(&e4[(size_t)(k0 + k) * 32 + n4]);
        tile[(n4 * 4 + 0) * 65 + k] = f2bf(f.x);
        tile[(n4 * 4 + 1) * 65 + k] = f2bf(f.y);
        tile[(n4 * 4 + 2) * 65 + k] = f2bf(f.z);
        tile[(n4 * 4 + 3) * 65 + k] = f2bf(f.w);
    }
    __syncthreads();
    #pragma unroll
    for (int c = 0; c < 4; ++c) {
        int l8 = c * 256 + tid;      // n*8 + seg
        int n = l8 >> 3, seg = l8 & 7;
        int kk = k0 + seg * 8;
        if (kk < V_) {
            short8 v;
            #pragma unroll
            for (int i = 0; i < 8; ++i) v[i] = (short)tile[n * 65 + seg * 8 + i];
            *(short8*)(embT + (size_t)n * V_ + kk) = v;
        }
    }
}

// ---------------------------------------------------------------- big GEMM: partial[ks][3328][128] = rows @ emb
// BM=64 tile, ks=8 (416 blocks all co-resident). rows 0..3199 = x,
// 3200..3231 = a, rest padding. Double-buffered LDS, B staged via
// global_load_lds DMA, A prefetched in regs with NONTEMPORAL loads (x is
// streamed once — nt keeps the LLC-resident embT hot in L2 for the B-DMA).
// Plain stores (NO atomics — round-1 showed ks*full-size atomics cost ~35 us).
__global__ __launch_bounds__(256, 4) void big_gemm(const float* __restrict__ x,
                                                   const float* __restrict__ a,
                                                   const unsigned short* __restrict__ embT,
                                                   float* __restrict__ partial,
                                                   int ks) {
    __shared__ unsigned short Alds[2][64 * 40];    // bf16, padded stride 40
    __shared__ unsigned short Blds[2][128 * 32];   // bf16, unpadded (DMA target)
    int tid = threadIdx.x;
    int bx = blockIdx.x, by = blockIdx.y;
    int m0 = bx * 64;
    int per = 625 / ks, extra = 625 % ks;
    int kb0 = by * per + (by < extra ? by : extra);
    int nkb = per + (by < extra ? 1 : 0);

    int lane = tid & 63, wave = tid >> 6;
    int wr = wave >> 1, wc = wave & 1;             // wave-tile: 32 rows x 64 cols
    int ln = lane & 15, quad = lane >> 4;

    float4v acc[2][4];
    #pragma unroll
    for (int i = 0; i < 2; ++i)
        #pragma unroll
        for (int j = 0; j < 4; ++j) acc[i][j] = (float4v){0.f, 0.f, 0.f, 0.f};

    int row = tid >> 2, kseg = tid & 3;            // 64 rows x 4 k-segments (8 floats each)
    int rg = m0 + row;
    int aidx = rg - 3200; aidx = aidx < 0 ? 0 : (aidx > 31 ? 31 : aidx);
    const float* __restrict__ srcA = (rg < 3200) ? (x + (size_t)rg * V_)
                                                 : (a + (size_t)aidx * V_);
    // B DMA mapping: call q in {0,1}: chunk c = q*256 + tid; brow=c>>2, bkq=c&3
    int brow0 = tid >> 2, bkq = tid & 3;
    int wbase = tid & ~63;                     // wave-uniform chunk base (q=0)
    const unsigned short* gB0 = embT + (size_t)brow0 * V_ + bkq * 8;
    const unsigned short* gB1 = embT + (size_t)(64 + brow0) * V_ + bkq * 8;

    float4v fa0, fa1;

    // ---- prologue: stage tile 0 into buf 0
    {
        int k0 = kb0 * 32;
        const float4v* ap = (const float4v*)(srcA + k0 + kseg * 8);
        fa0 = __builtin_nontemporal_load(ap);
        fa1 = __builtin_nontemporal_load(ap + 1);
        GLL16(gB0 + k0, &Blds[0][(size_t)wbase * 8]);
        GLL16(gB1 + k0, &Blds[0][(size_t)(256 + wbase) * 8]);
        short8 w0;
        w0[0]=(short)f2bf(fa0.x); w0[1]=(short)f2bf(fa0.y); w0[2]=(short)f2bf(fa0.z); w0[3]=(short)f2bf(fa0.w);
        w0[4]=(short)f2bf(fa1.x); w0[5]=(short)f2bf(fa1.y); w0[6]=(short)f2bf(fa1.z); w0[7]=(short)f2bf(fa1.w);
        *(short8*)&Alds[0][row * 40 + kseg * 8] = w0;
    }
    __syncthreads();

    for (int it = 0; it < nkb; ++it) {
        int buf = it & 1, nxt = buf ^ 1;
        bool more = (it + 1 < nkb);
        if (more) {
            int k0 = (kb0 + it + 1) * 32;
            const float4v* ap = (const float4v*)(srcA + k0 + kseg * 8);
            fa0 = __builtin_nontemporal_load(ap);
            fa1 = __builtin_nontemporal_load(ap + 1);
            GLL16(gB0 + k0, &Blds[nxt][(size_t)wbase * 8]);
            GLL16(gB1 + k0, &Blds[nxt][(size_t)(256 + wbase) * 8]);
        }
        short8 af[2];
        #pragma unroll
        for (int i = 0; i < 2; ++i)
            af[i] = *(const short8*)&Alds[buf][(wr * 32 + i * 16 + ln) * 40 + quad * 8];
        #pragma unroll
        for (int j = 0; j < 4; ++j) {
            short8 bf = *(const short8*)&Blds[buf][(wc * 64 + j * 16 + ln) * 32 + quad * 8];
            #pragma unroll
            for (int i = 0; i < 2; ++i)
                acc[i][j] = __builtin_amdgcn_mfma_f32_16x16x32_bf16(af[i], bf, acc[i][j], 0, 0, 0);
        }
        if (more) {
            short8 w0;
            w0[0]=(short)f2bf(fa0.x); w0[1]=(short)f2bf(fa0.y); w0[2]=(short)f2bf(fa0.z); w0[3]=(short)f2bf(fa0.w);
            w0[4]=(short)f2bf(fa1.x); w0[5]=(short)f2bf(fa1.y); w0[6]=(short)f2bf(fa1.z); w0[7]=(short)f2bf(fa1.w);
            *(short8*)&Alds[nxt][row * 40 + kseg * 8] = w0;
        }
        __syncthreads();
    }

    float* dst = partial + (size_t)by * 3328 * 128;
    #pragma unroll
    for (int i = 0; i < 2; ++i) {
        #pragma unroll
        for (int j = 0; j < 4; ++j) {
            int rowb = m0 + wr * 32 + i * 16 + quad * 4;
            int col = wc * 64 + j * 16 + ln;
            #pragma unroll
            for (int r = 0; r < 4; ++r)
                dst[(size_t)(rowb + r) * 128 + col] = acc[i][j][r];
        }
    }
}

// ---------------------------------------------------------------- fused: ks-sum + tanh + mask -> xproj = xe @ gru_k + b_i
// blocks 0..199: 16 x-rows each. block 200: ae rows. blocks 201..216: LLC
// prewarm of gru_rk + W1 (gru's 32 blocks otherwise each pull 196 KB at
// per-CU HBM BW — prewarm makes those reads LLC hits).
__global__ __launch_bounds__(384) void xproj_fused(const float* __restrict__ partial,
                                                   const float* __restrict__ gru_k,
                                                   const float* __restrict__ b_i,
                                                   const float* __restrict__ gru_rk,
                                                   const float* __restrict__ W1,
                                                   float* __restrict__ xproj,
                                                   float* __restrict__ maskg,
                                                   float* __restrict__ ae,
                                                   int ks) {
    const size_t SL = (size_t)3328 * 128;          // slice stride (floats)
    int tid = threadIdx.x;
    if (blockIdx.x > 200) {                        // LLC prewarm (reads kept live)
        int pb = blockIdx.x - 201;                 // 0..15
        int idx = pb * 384 + tid;                  // 0..6143
        const float4v* rk4 = (const float4v*)gru_rk;   // 12288 float4
        float4v v1 = rk4[idx];
        float4v v2 = rk4[idx + 6144];
        float s = v1.x + v2.x;
        if (idx < 2080) { float4v v3 = ((const float4v*)W1)[idx]; s += v3.x; }
        asm volatile("" :: "v"(s));
        return;
    }
    if (blockIdx.x == 200) {                       // a-embedding rows 3200..3231
        for (int i = tid; i < 32 * 128; i += 384) {
            float s = 0.f;
            for (int k = 0; k < ks; ++k) s += partial[(size_t)k * SL + 3200 * 128 + i];
            ae[i] = fast_tanh(s);
        }
        return;
    }
    __shared__ float xs[16 * 128];
    __shared__ int anyr[16];
    int row0 = blockIdx.x * 16;
    if (tid < 16) anyr[tid] = 0;
    __syncthreads();
    const float4v* p4 = (const float4v*)partial + (size_t)row0 * 32;  // 32 float4 per row
    const size_t SL4 = SL / 4;
    for (int i4 = tid; i4 < 512; i4 += 384) {
        float4v s = p4[i4];
        for (int k = 1; k < ks; ++k) {
            float4v t = p4[(size_t)k * SL4 + i4];
            s.x += t.x; s.y += t.y; s.z += t.z; s.w += t.w;
        }
        float4v v;
        v.x = fast_tanh(s.x); v.y = fast_tanh(s.y);
        v.z = fast_tanh(s.z); v.w = fast_tanh(s.w);
        *(float4v*)&xs[i4 * 4] = v;
        if (v.x != 0.f || v.y != 0.f || v.z != 0.f || v.w != 0.f)
            anyr[i4 >> 5] = 1;                     // benign race: all writers store 1
    }
    __syncthreads();
    if (tid < 16) maskg[row0 + tid] = anyr[tid] ? 1.f : 0.f;

    int j = tid;  // 0..383
    float2v acc[16];
    #pragma unroll
    for (int r = 0; r < 16; ++r) acc[r] = (float2v){0.f, 0.f};
    float bi = b_i[j];
    for (int k4 = 0; k4 < 32; ++k4) {
        float2v g01 = { gru_k[(k4 * 4 + 0) * 384 + j], gru_k[(k4 * 4 + 1) * 384 + j] };
        float2v g23 = { gru_k[(k4 * 4 + 2) * 384 + j], gru_k[(k4 * 4 + 3) * 384 + j] };
        #pragma unroll
        for (int r = 0; r < 16; ++r) {
            float4v xv = *(const float4v*)&xs[r * 128 + k4 * 4];
            float2v x01 = {xv.x, xv.y}, x23 = {xv.z, xv.w};
            acc[r] = __builtin_elementwise_fma(x01, g01, acc[r]);
            acc[r] = __builtin_elementwise_fma(x23, g23, acc[r]);
        }
    }
    #pragma unroll
    for (int r = 0; r < 16; ++r)
        xproj[(size_t)(row0 + r) * 384 + j] = (acc[r].x + acc[r].y) + bi;
}

// ---------------------------------------------------------------- GRU scan + fused head: 1 block / batch
// Packed-f32 FMA matvec (half the issue cycles) + exact tail-trim: mask is
// contiguous-trailing (x rows zeroed for t>=len), masked steps are identity.
__global__ __launch_bounds__(384) void gru_fused(const float* __restrict__ xproj,
                                                 const float* __restrict__ maskg,
                                                 const float* __restrict__ gru_rk,
                                                 const float* __restrict__ b_r,
                                                 const float* __restrict__ ae,
                                                 const float* __restrict__ d,
                                                 const float* __restrict__ W1,
                                                 const float* __restrict__ b1,
                                                 const float* __restrict__ W2,
                                                 const float* __restrict__ b2,
                                                 float* __restrict__ out) {
    int b = blockIdx.x;
    int j = threadIdx.x;  // 0..383
    float2v wv[64];       // wv[i] = {rk[2i][j], rk[2i+1][j]}
    #pragma unroll
    for (int i = 0; i < 64; ++i) {
        wv[i] = (float2v){ gru_rk[(2 * i) * 384 + j], gru_rk[(2 * i + 1) * 384 + j] };
    }
    float br = b_r[j];
    __shared__ float4v hs4[32];
    __shared__ float recs[384];
    __shared__ int ntS;
    float* hs = (float*)hs4;
    float hreg = 0.f;
    if (j == 0) ntS = 0;
    if (j < 128) hs[j] = 0.f;
    const float* xp_base = xproj + (size_t)b * 100 * 384;
    const float* mk = maskg + b * 100;
    // prefetched gate inputs for j<128 threads
    float xz = 0.f, xr = 0.f, xh = 0.f;
    if (j < 128) { xz = xp_base[j]; xr = xp_base[128 + j]; xh = xp_base[256 + j]; }
    __syncthreads();
    if (j < 100 && mk[j] != 0.f) atomicMax(&ntS, j + 1);
    __syncthreads();
    int nt = ntS;         // steps t>=nt have mask 0 -> h unchanged (exact skip)
    for (int t = 0; t < nt; ++t) {
        // prefetch next step's gate inputs (latency hidden behind matvec + gates)
        float nxz = 0.f, nxr = 0.f, nxh = 0.f;
        if (t + 1 < nt && j < 128) {
            const float* nb = xp_base + (t + 1) * 384;
            nxz = nb[j]; nxr = nb[128 + j]; nxh = nb[256 + j];
        }
        float2v a0 = {0.f, 0.f}, a1 = {0.f, 0.f}, a2 = {0.f, 0.f}, a3 = {0.f, 0.f};
        #pragma unroll
        for (int k4 = 0; k4 < 32; k4 += 2) {
            float4v hA = hs4[k4], hB = hs4[k4 + 1];
            float2v hA0 = {hA.x, hA.y}, hA1 = {hA.z, hA.w};
            float2v hB0 = {hB.x, hB.y}, hB1 = {hB.z, hB.w};
            a0 = __builtin_elementwise_fma(hA0, wv[2 * k4 + 0], a0);
            a1 = __builtin_elementwise_fma(hA1, wv[2 * k4 + 1], a1);
            a2 = __builtin_elementwise_fma(hB0, wv[2 * k4 + 2], a2);
            a3 = __builtin_elementwise_fma(hB1, wv[2 * k4 + 3], a3);
        }
        recs[j] = br + (((a0.x + a0.y) + (a1.x + a1.y)) + ((a2.x + a2.y) + (a3.x + a3.y)));
        __syncthreads();
        if (j < 128) {
            float z = sigmoidf_(xz + recs[j]);
            float r = sigmoidf_(xr + recs[128 + j]);
            float hh = fast_tanh(xh + r * recs[256 + j]);
            float hn = z * hreg + (1.f - z) * hh;
            hreg = (mk[t] != 0.f) ? hn : hreg;
            hs[j] = hreg;
        }
        __syncthreads();
        xz = nxz; xr = nxr; xh = nxh;
    }
    // ---- fused head: h is complete in hs[] after the final barrier
    if (j < 64) {
        int m = j;
        float s = b1[m];
        const float* ab = ae + b * 128;
        #pragma unroll 4
        for (int k = 0; k < 128; ++k) s = fmaf(hs[k], W1[k * 64 + m], s);
        #pragma unroll 4
        for (int k = 0; k < 128; ++k) s = fmaf(ab[k], W1[(128 + k) * 64 + m], s);
        float c = fast_tanh(s);
        float p = c * W2[m];
        #pragma unroll
        for (int off = 32; off > 0; off >>= 1) p += __shfl_down(p, off);
        if (m == 0) {
            p += d[b * 2 + 0] * W2[64] + d[b * 2 + 1] * W2[65] + b2[0];
            out[b] = sigmoidf_(p);
        }
    }
}

extern "C" void kernel_launch(void* const* d_in, const int* in_sizes, int n_in,
                              void* d_out, int out_size, void* d_ws, size_t ws_size,
                              hipStream_t stream) {
    (void)in_sizes; (void)n_in; (void)out_size;
    const float* x      = (const float*)d_in[0];
    const float* a      = (const float*)d_in[1];
    const float* d      = (const float*)d_in[2];
    const float* emb    = (const float*)d_in[3];
    const float* gru_k  = (const float*)d_in[4];
    const float* gru_rk = (const float*)d_in[5];
    const float* gbi    = (const float*)d_in[6];
    const float* gbr    = (const float*)d_in[7];
    const float* W1     = (const float*)d_in[8];
    const float* b1     = (const float*)d_in[9];
    const float* W2     = (const float*)d_in[10];
    const float* b2     = (const float*)d_in[11];
    float* out = (float*)d_out;

    char* ws = (char*)d_ws;
    unsigned short* embT = (unsigned short*)(ws);              //  5,120,000 B
    const size_t slice = (size_t)3328 * 128 * 4;               //  1,703,936 B
    float* partial = (float*)(ws + 5120000);

    // split-K slices: 8 preferred (52x8 = 416 blocks, 13.6 MB partial)
    int ks = 8;
    {
        size_t fixed_rest = 16384 + 12800 + 4915200;           // ae + maskg + xproj
        while (ks > 1 && 5120000 + (size_t)ks * slice + fixed_rest > ws_size) ks >>= 1;
    }
    char* after = ws + 5120000 + (size_t)ks * slice;
    float* ae      = (float*)(after);                          //     16,384 B
    float* maskg   = (float*)(after + 16384);                  //     12,800 B
    float* xproj   = (float*)(after + 29184);                  //  4,915,200 B

    hipLaunchKernelGGL(cvt_embT,    dim3(313),    dim3(256), 0, stream, emb, embT);
    hipLaunchKernelGGL(big_gemm,    dim3(52, ks), dim3(256), 0, stream, x, a, embT, partial, ks);
    hipLaunchKernelGGL(xproj_fused, dim3(217),    dim3(384), 0, stream, partial, gru_k, gbi,
                       gru_rk, W1, xproj, maskg, ae, ks);
    hipLaunchKernelGGL(gru_fused,   dim3(32),     dim3(384), 0, stream, xproj, maskg, gru_rk, gbr,
                       ae, d, W1, b1, W2, b2, out);
}